// Round 1
// baseline (5154.649 us; speedup 1.0000x reference)
//
#include <hip/hip_runtime.h>
#include <math.h>

// Problem dims (fixed by reference setup_inputs)
constexpr int kB = 8;
constexpr int kC = 256;     // channels
constexpr int kM = 128;     // C/2
constexpr int kN = 16384;   // H*W = 128*128
constexpr int kSplits = 64; // blocks per batch (each handles N/kSplits pixels)
constexpr int kPix = 16;    // pixels per chunk
constexpr int kChunks = (kN / kSplits) / kPix; // 16
constexpr float kEps = 1e-6f;

// workspace layout (floats)
constexpr size_t kMatOff  = 0;                          // matrix [B][M][C]
constexpr size_t kKsumOff = (size_t)kB * kM * kC;       // Ksum   [B][M]
constexpr size_t kVsumOff = kKsumOff + (size_t)kB * kM; // vsum   [B][C]
constexpr size_t kWsFloats = kVsumOff + (size_t)kB * kC;

__global__ void zero_ws_kernel(float* __restrict__ ws) {
  size_t i = (size_t)blockIdx.x * blockDim.x + threadIdx.x;
  if (i < kWsFloats) ws[i] = 0.0f;
}

// Pass 1: K = norm(Wk x + bk), V = Wv x + bv; accumulate
//   matrix[b] += Kn_chunk @ V_chunk^T ; Ksum += sum Kn ; vsum += sum V
__global__ __launch_bounds__(256, 2)
void acc_kernel(const float* __restrict__ x,
                const float* __restrict__ Wk, const float* __restrict__ bk,
                const float* __restrict__ Wv, const float* __restrict__ bv,
                float* __restrict__ ws)
{
  __shared__ float xs[kC][kPix];        // x chunk, [channel][pixel]
  __shared__ float kbuf[kM][kPix + 1];  // normalized K
  __shared__ float vbuf[kC][kPix + 1];  // V
  __shared__ float red[kPix][17];
  __shared__ float invs[kPix];

  float* matrix = ws + kMatOff;
  float* Ksum   = ws + kKsumOff;
  float* vsum   = ws + kVsumOff;

  const int t  = threadIdx.x;
  const int tp = t & 15;   // pixel
  const int tg = t >> 4;   // 0..15 group
  const int b  = blockIdx.y;
  const int base = blockIdx.x * (kN / kSplits);
  const int r0 = tg * 8;   // owned K rows (and matrix rows)
  const int v0 = tg * 16;  // owned V rows

  const float4* Wk4 = reinterpret_cast<const float4*>(Wk);
  const float4* Wv4 = reinterpret_cast<const float4*>(Wv);

  // per-block partial of matrix: thread owns rows r0..r0+8, cols {j*16+tp}
  float accm[8][16];
#pragma unroll
  for (int i = 0; i < 8; ++i)
#pragma unroll
    for (int j = 0; j < 16; ++j) accm[i][j] = 0.0f;
  float ksum_acc[8];
#pragma unroll
  for (int i = 0; i < 8; ++i) ksum_acc[i] = 0.0f;
  float vsum_acc[16];
#pragma unroll
  for (int j = 0; j < 16; ++j) vsum_acc[j] = 0.0f;

  for (int ch = 0; ch < kChunks; ++ch) {
    const int n0 = base + ch * kPix;
    __syncthreads();  // protect LDS reuse across chunks
#pragma unroll
    for (int pass = 0; pass < 16; ++pass) {
      const int c = pass * 16 + tg;
      xs[c][tp] = x[((size_t)(b * kC + c)) * kN + n0 + tp];
    }
    __syncthreads();

    // ---- K projection: rows r0..r0+8 for pixel tp ----
    float acck[8];
#pragma unroll
    for (int i = 0; i < 8; ++i) acck[i] = bk[r0 + i];
    for (int c4 = 0; c4 < kC / 4; ++c4) {
      const float x0 = xs[c4 * 4 + 0][tp];
      const float x1 = xs[c4 * 4 + 1][tp];
      const float x2 = xs[c4 * 4 + 2][tp];
      const float x3 = xs[c4 * 4 + 3][tp];
#pragma unroll
      for (int i = 0; i < 8; ++i) {
        const float4 w = Wk4[(r0 + i) * (kC / 4) + c4];
        acck[i] += w.x * x0 + w.y * x1 + w.z * x2 + w.w * x3;
      }
    }
    // per-pixel sum of squares over all 128 rows
    float ssq = 0.0f;
#pragma unroll
    for (int i = 0; i < 8; ++i) ssq += acck[i] * acck[i];
    red[tp][tg] = ssq;
    __syncthreads();
    if (t < kPix) {
      float s = 0.0f;
#pragma unroll
      for (int gi = 0; gi < 16; ++gi) s += red[t][gi];
      invs[t] = 1.0f / sqrtf(s);
    }
    __syncthreads();
    const float iv = invs[tp];
#pragma unroll
    for (int i = 0; i < 8; ++i) {
      const float kn = acck[i] * iv;
      kbuf[r0 + i][tp] = kn;
      ksum_acc[i] += kn;
    }

    // ---- V projection: rows v0..v0+16 for pixel tp ----
    float accv[16];
#pragma unroll
    for (int j = 0; j < 16; ++j) accv[j] = bv[v0 + j];
    for (int c4 = 0; c4 < kC / 4; ++c4) {
      const float x0 = xs[c4 * 4 + 0][tp];
      const float x1 = xs[c4 * 4 + 1][tp];
      const float x2 = xs[c4 * 4 + 2][tp];
      const float x3 = xs[c4 * 4 + 3][tp];
#pragma unroll
      for (int j = 0; j < 16; ++j) {
        const float4 w = Wv4[(v0 + j) * (kC / 4) + c4];
        accv[j] += w.x * x0 + w.y * x1 + w.z * x2 + w.w * x3;
      }
    }
#pragma unroll
    for (int j = 0; j < 16; ++j) {
      vbuf[v0 + j][tp] = accv[j];
      vsum_acc[j] += accv[j];
    }
    __syncthreads();

    // ---- outer-product accumulate: matrix += kn (x) v over 16 pixels ----
#pragma unroll
    for (int p = 0; p < kPix; ++p) {
      float kv[8];
#pragma unroll
      for (int i = 0; i < 8; ++i) kv[i] = kbuf[r0 + i][p];  // broadcast, free
      float vv[16];
#pragma unroll
      for (int j = 0; j < 16; ++j) vv[j] = vbuf[j * 16 + tp][p];  // 17-stride: conflict-free
#pragma unroll
      for (int i = 0; i < 8; ++i)
#pragma unroll
        for (int j = 0; j < 16; ++j) accm[i][j] += kv[i] * vv[j];
    }
  }

  // flush partials (one pass per block)
  float* mb = matrix + (size_t)b * kM * kC;
#pragma unroll
  for (int i = 0; i < 8; ++i)
#pragma unroll
    for (int j = 0; j < 16; ++j)
      atomicAdd(&mb[(size_t)(r0 + i) * kC + j * 16 + tp], accm[i][j]);
#pragma unroll
  for (int i = 0; i < 8; ++i) atomicAdd(&Ksum[b * kM + r0 + i], ksum_acc[i]);
#pragma unroll
  for (int j = 0; j < 16; ++j) atomicAdd(&vsum[b * kC + v0 + j], vsum_acc[j]);
}

// Pass 2: Qn = norm(Wq x + bq); tailor = 1/(N + Qn.(Ksum+eps));
//         out = gamma * (vsum + matrix^T Qn) * tailor
__global__ __launch_bounds__(256, 2)
void out_kernel(const float* __restrict__ x,
                const float* __restrict__ Wq, const float* __restrict__ bq,
                const float* __restrict__ ws,
                const float* __restrict__ gamma,
                float* __restrict__ out)
{
  __shared__ float xs[kC][kPix];
  __shared__ float qbuf[kM][kPix + 1];
  __shared__ float red[kPix][17];
  __shared__ float red2[kPix][17];
  __shared__ float invs[kPix];
  __shared__ float tails[kPix];

  const float* matrix = ws + kMatOff;
  const float* Ksum   = ws + kKsumOff;
  const float* vsum   = ws + kVsumOff;

  const int t  = threadIdx.x;
  const int tp = t & 15;
  const int tg = t >> 4;
  const int b  = blockIdx.y;
  const int base = blockIdx.x * (kN / kSplits);
  const int r0 = tg * 8;   // owned Q rows
  const int c0 = tg * 16;  // owned output channels
  const float gm = gamma[0];
  const float4* Wq4 = reinterpret_cast<const float4*>(Wq);

  for (int ch = 0; ch < kChunks; ++ch) {
    const int n0 = base + ch * kPix;
    __syncthreads();
#pragma unroll
    for (int pass = 0; pass < 16; ++pass) {
      const int c = pass * 16 + tg;
      xs[c][tp] = x[((size_t)(b * kC + c)) * kN + n0 + tp];
    }
    __syncthreads();

    // Q projection
    float accq[8];
#pragma unroll
    for (int i = 0; i < 8; ++i) accq[i] = bq[r0 + i];
    for (int c4 = 0; c4 < kC / 4; ++c4) {
      const float x0 = xs[c4 * 4 + 0][tp];
      const float x1 = xs[c4 * 4 + 1][tp];
      const float x2 = xs[c4 * 4 + 2][tp];
      const float x3 = xs[c4 * 4 + 3][tp];
#pragma unroll
      for (int i = 0; i < 8; ++i) {
        const float4 w = Wq4[(r0 + i) * (kC / 4) + c4];
        accq[i] += w.x * x0 + w.y * x1 + w.z * x2 + w.w * x3;
      }
    }

    float ssq = 0.0f, dot = 0.0f;
#pragma unroll
    for (int i = 0; i < 8; ++i) {
      ssq += accq[i] * accq[i];
      dot += accq[i] * (Ksum[b * kM + r0 + i] + kEps);
    }
    red[tp][tg] = ssq;
    red2[tp][tg] = dot;
    __syncthreads();
    if (t < kPix) {
      float s = 0.0f, d = 0.0f;
#pragma unroll
      for (int gi = 0; gi < 16; ++gi) { s += red[t][gi]; d += red2[t][gi]; }
      const float iv = 1.0f / sqrtf(s);
      invs[t] = iv;
      tails[t] = 1.0f / ((float)kN + d * iv);
    }
    __syncthreads();
    const float iv = invs[tp];
#pragma unroll
    for (int i = 0; i < 8; ++i) qbuf[r0 + i][tp] = accq[i] * iv;
    __syncthreads();

    // out[c, tp] = gamma * (vsum[c] + sum_m qn[m]*matrix[m][c]) * tailor
    float acco[16];
#pragma unroll
    for (int j = 0; j < 16; ++j) acco[j] = vsum[b * kC + c0 + j];
    for (int m = 0; m < kM; ++m) {
      const float qv = qbuf[m][tp];
      const float4* mr =
          reinterpret_cast<const float4*>(matrix + ((size_t)(b * kM + m)) * kC + c0);
#pragma unroll
      for (int j4 = 0; j4 < 4; ++j4) {
        const float4 w = mr[j4];
        acco[j4 * 4 + 0] += qv * w.x;
        acco[j4 * 4 + 1] += qv * w.y;
        acco[j4 * 4 + 2] += qv * w.z;
        acco[j4 * 4 + 3] += qv * w.w;
      }
    }
    const float scale = tails[tp] * gm;
#pragma unroll
    for (int j = 0; j < 16; ++j)
      out[((size_t)(b * kC + c0 + j)) * kN + n0 + tp] = acco[j] * scale;
  }
}

extern "C" void kernel_launch(void* const* d_in, const int* in_sizes, int n_in,
                              void* d_out, int out_size, void* d_ws, size_t ws_size,
                              hipStream_t stream) {
  const float* x     = (const float*)d_in[0];
  const float* Wq    = (const float*)d_in[1];
  const float* bq    = (const float*)d_in[2];
  const float* Wk    = (const float*)d_in[3];
  const float* bk    = (const float*)d_in[4];
  const float* Wv    = (const float*)d_in[5];
  const float* bv    = (const float*)d_in[6];
  const float* gamma = (const float*)d_in[7];
  float* out = (float*)d_out;
  float* ws  = (float*)d_ws;  // needs ~1.04 MiB

  zero_ws_kernel<<<(int)((kWsFloats + 255) / 256), 256, 0, stream>>>(ws);
  acc_kernel<<<dim3(kSplits, kB), 256, 0, stream>>>(x, Wk, bk, Wv, bv, ws);
  out_kernel<<<dim3(kSplits, kB), 256, 0, stream>>>(x, Wq, bq, ws, gamma, out);
}

// Round 2
// 470.579 us; speedup vs baseline: 10.9538x; 10.9538x over previous
//
#include <hip/hip_runtime.h>
#include <math.h>

typedef unsigned short ushort_t;
typedef __attribute__((ext_vector_type(4))) float f32x4;
typedef __attribute__((ext_vector_type(8))) short short8;

#define MFMA16(a, b, c) __builtin_amdgcn_mfma_f32_16x16x32_bf16((a), (b), (c), 0, 0, 0)

// Problem dims (fixed)
constexpr int kB = 8;
constexpr int kC = 256;
constexpr int kM = 128;
constexpr int kN = 16384;

// ws layout (bytes, all 256-aligned). Total 1,724,416 B (~1.65 MB).
constexpr size_t kOffS    = 0;         // fp32 [8][128][256]
constexpr size_t kOffKsum = 1048576;   // fp32 [8][128]
constexpr size_t kOffXsum = 1052672;   // fp32 [8][256]
constexpr size_t kOffVsum = 1060864;   // fp32 [8][256]
constexpr size_t kOffWkb  = 1069056;   // bf16 [128][256]
constexpr size_t kOffWqb  = 1134592;   // bf16 [128][256]
constexpr size_t kOffMatT = 1200128;   // bf16 [8][256][128]  (matrix transposed)

__device__ __forceinline__ ushort_t f2bf(float f) {
  union { float f; unsigned u; } v; v.f = f;
  unsigned r = v.u + 0x7fffu + ((v.u >> 16) & 1u);
  return (ushort_t)(r >> 16);
}

// ---------------- K0: zero accumulators + cast weights to bf16 ----------------
__global__ void k0_init(const float* __restrict__ Wq, const float* __restrict__ Wk,
                        float* __restrict__ ws_f, ushort_t* __restrict__ Wkb,
                        ushort_t* __restrict__ Wqb) {
  int i = blockIdx.x * 256 + threadIdx.x;  // grid: 1024 x 256 = 262144 threads
  // zero S (262144 f) + Ksum (1024 f) + xsum (2048 f) = 265216 contiguous floats
  for (int j = i; j < 265216; j += 262144) ws_f[j] = 0.0f;
  if (i < kM * kC) {
    Wkb[i] = f2bf(Wk[i]);
    Wqb[i] = f2bf(Wq[i]);
  }
}

// ---------------- K1: K-proj (MFMA) -> L2-norm -> S += Kn * x^T (MFMA) -------
// grid (64, 8), block 512. Each block: 8 tiles of 32 pixels (256 px total).
__global__ __launch_bounds__(512, 2)
void k1_acc(const float* __restrict__ x, const float* __restrict__ bk,
            const ushort_t* __restrict__ Wkb, float* __restrict__ S,
            float* __restrict__ Ksum, float* __restrict__ xsum) {
  __shared__ __align__(16) ushort_t xb_n[256][40];   // [ch][px]  (px-fastest)
  __shared__ __align__(16) ushort_t xb_t[32][264];   // [px][ch]  (ch-fastest)
  __shared__ __align__(16) ushort_t knb[128][40];    // [Krow][px]
  __shared__ float red[8][32];
  __shared__ float inv_s[32];

  const int t = threadIdx.x;
  const int b = blockIdx.y;
  const int lane = t & 63, w = t >> 6, quad = lane >> 4, l16 = lane & 15;
  const int ch = t >> 1, half = t & 1;

  float bk_r[4];
#pragma unroll
  for (int r = 0; r < 4; ++r) bk_r[r] = bk[16 * w + 4 * quad + r];

  f32x4 accS[16];
#pragma unroll
  for (int ct = 0; ct < 16; ++ct) accS[ct] = (f32x4){0.f, 0.f, 0.f, 0.f};
  float ksump[4] = {0.f, 0.f, 0.f, 0.f};
  float xsum_priv = 0.f;

  const float* xrow = x + ((size_t)(b * kC + ch)) * kN;

  for (int ti = 0; ti < 8; ++ti) {
    const int n0 = blockIdx.x * 256 + ti * 32;
    __syncthreads();  // protect LDS from previous tile's readers

    // ---- stage x tile: fp32 -> bf16, two layouts ----
    const float4* xg = (const float4*)(xrow + n0 + half * 16);
    float vals[16];
#pragma unroll
    for (int i = 0; i < 4; ++i) {
      float4 v = xg[i];
      vals[4 * i + 0] = v.x; vals[4 * i + 1] = v.y;
      vals[4 * i + 2] = v.z; vals[4 * i + 3] = v.w;
    }
    ushort_t u[16];
#pragma unroll
    for (int i = 0; i < 16; ++i) { u[i] = f2bf(vals[i]); xsum_priv += vals[i]; }
#pragma unroll
    for (int i = 0; i < 4; ++i) {
      uint2 p;
      p.x = (unsigned)u[4 * i] | ((unsigned)u[4 * i + 1] << 16);
      p.y = (unsigned)u[4 * i + 2] | ((unsigned)u[4 * i + 3] << 16);
      *(uint2*)&xb_n[ch][half * 16 + 4 * i] = p;
    }
#pragma unroll
    for (int i = 0; i < 16; ++i) xb_t[half * 16 + i][ch] = u[i];
    __syncthreads();

    // ---- GEMM1: K[128x32] = Wk * x (wave w owns K rows 16w..16w+16) ----
    f32x4 acc1[2] = {{0.f, 0.f, 0.f, 0.f}, {0.f, 0.f, 0.f, 0.f}};
    const ushort_t* wkbase = Wkb + (16 * w + l16) * 256 + quad * 8;
#pragma unroll
    for (int ks = 0; ks < 8; ++ks) {
      short8 a = *(const short8*)(wkbase + ks * 32);
      short8 b0 = *(const short8*)&xb_t[l16][ks * 32 + quad * 8];
      short8 b1 = *(const short8*)&xb_t[16 + l16][ks * 32 + quad * 8];
      acc1[0] = MFMA16(a, b0, acc1[0]);
      acc1[1] = MFMA16(a, b1, acc1[1]);
    }
    // add bias, column sum-of-squares (per pixel over 128 rows)
    float k0v[4], k1v[4];
    float ssq0 = 0.f, ssq1 = 0.f;
#pragma unroll
    for (int r = 0; r < 4; ++r) {
      k0v[r] = acc1[0][r] + bk_r[r];
      k1v[r] = acc1[1][r] + bk_r[r];
      ssq0 += k0v[r] * k0v[r];
      ssq1 += k1v[r] * k1v[r];
    }
    ssq0 += __shfl_xor(ssq0, 16); ssq0 += __shfl_xor(ssq0, 32);
    ssq1 += __shfl_xor(ssq1, 16); ssq1 += __shfl_xor(ssq1, 32);
    if (quad == 0) { red[w][l16] = ssq0; red[w][16 + l16] = ssq1; }
    __syncthreads();
    if (t < 32) {
      float s = 0.f;
#pragma unroll
      for (int ww = 0; ww < 8; ++ww) s += red[ww][t];
      inv_s[t] = rsqrtf(s);
    }
    __syncthreads();
    const float iv0 = inv_s[l16], iv1 = inv_s[16 + l16];
#pragma unroll
    for (int r = 0; r < 4; ++r) {
      float kn0 = k0v[r] * iv0, kn1 = k1v[r] * iv1;
      ksump[r] += kn0 + kn1;
      knb[16 * w + 4 * quad + r][l16] = f2bf(kn0);
      knb[16 * w + 4 * quad + r][16 + l16] = f2bf(kn1);
    }
    __syncthreads();

    // ---- GEMM2: S[128x256] += Kn * x^T (Kdim = 32 px, one MFMA per c-tile) --
    short8 a2 = *(const short8*)&knb[16 * w + l16][quad * 8];
#pragma unroll
    for (int ct = 0; ct < 16; ++ct) {
      short8 b2 = *(const short8*)&xb_n[ct * 16 + l16][quad * 8];
      accS[ct] = MFMA16(a2, b2, accS[ct]);
    }
  }

  // ---- flush ----
  float* Sb = S + (size_t)b * kM * kC;
#pragma unroll
  for (int ct = 0; ct < 16; ++ct)
#pragma unroll
    for (int r = 0; r < 4; ++r)
      atomicAdd(&Sb[(16 * w + 4 * quad + r) * 256 + ct * 16 + l16], accS[ct][r]);
#pragma unroll
  for (int r = 0; r < 4; ++r) {
    float v = ksump[r];
    v += __shfl_xor(v, 1); v += __shfl_xor(v, 2);
    v += __shfl_xor(v, 4); v += __shfl_xor(v, 8);
    if (l16 == 0) atomicAdd(&Ksum[b * kM + 16 * w + 4 * quad + r], v);
  }
  float xv = xsum_priv + __shfl_xor(xsum_priv, 1);
  if (!(t & 1)) atomicAdd(&xsum[b * kC + ch], xv);
}

// ---------------- K2: matrix = S*Wv^T + Ksum*bv^T (fp32), vsum --------------
// grid 64 (= 8 batch x 8 m-chunk), block 256.
__global__ __launch_bounds__(256, 2)
void k2_matrix(const float* __restrict__ S, const float* __restrict__ Ksum,
               const float* __restrict__ xsum, const float* __restrict__ Wv,
               const float* __restrict__ bv, ushort_t* __restrict__ matT,
               float* __restrict__ vsum) {
  __shared__ float Ss[16][256];
  __shared__ float Wvs[256][33];
  __shared__ float ksum_s[16];
  __shared__ float xsum_s[256];
  const int t = threadIdx.x;
  const int b = blockIdx.x >> 3, mc = blockIdx.x & 7;

  for (int i = 0; i < 16; ++i) Ss[i][t] = S[((size_t)b * kM + mc * 16 + i) * 256 + t];
  xsum_s[t] = xsum[b * kC + t];
  if (t < 16) ksum_s[t] = Ksum[b * kM + mc * 16 + t];

  float acc[16];
#pragma unroll
  for (int i = 0; i < 16; ++i) acc[i] = 0.f;
  float vacc = 0.f;

  for (int cb = 0; cb < 8; ++cb) {
    __syncthreads();
    for (int rr = 0; rr < 32; ++rr) {
      int c = rr * 8 + (t >> 5);
      Wvs[c][t & 31] = Wv[c * 256 + cb * 32 + (t & 31)];
    }
    __syncthreads();
#pragma unroll
    for (int j = 0; j < 32; ++j) {
      float wv = Wvs[t][j];
#pragma unroll
      for (int i = 0; i < 16; ++i) acc[i] += Ss[i][cb * 32 + j] * wv;
      vacc += xsum_s[cb * 32 + j] * wv;
    }
  }

  const float bvc = bv[t];
  ushort_t outp[16];
#pragma unroll
  for (int i = 0; i < 16; ++i) outp[i] = f2bf(acc[i] + ksum_s[i] * bvc);
  ushort_t* row = matT + ((size_t)b * kC + t) * kM + mc * 16;
#pragma unroll
  for (int i = 0; i < 8; ++i)
    ((unsigned*)row)[i] = (unsigned)outp[2 * i] | ((unsigned)outp[2 * i + 1] << 16);
  if (mc == 0) vsum[b * kC + t] = vacc + 16384.f * bvc;
}

// ---------------- K3: Q-proj -> norm/tailor -> out = g*t*(vsum + matT*qn) ----
// grid (64, 8), block 512.
__global__ __launch_bounds__(512, 2)
void k3_out(const float* __restrict__ x, const float* __restrict__ bq,
            const ushort_t* __restrict__ Wqb, const ushort_t* __restrict__ matT,
            const float* __restrict__ Ksum, const float* __restrict__ vsum,
            const float* __restrict__ gamma, float* __restrict__ out) {
  __shared__ __align__(16) ushort_t xb_t[32][264];
  __shared__ __align__(16) ushort_t qnb[32][136];  // [px][m]
  __shared__ float red[8][32], red2[8][32];
  __shared__ float inv_s[32], tail_s[32];

  const int t = threadIdx.x;
  const int b = blockIdx.y;
  const int lane = t & 63, w = t >> 6, quad = lane >> 4, l16 = lane & 15;
  const int ch = t >> 1, half = t & 1;
  const float gm = gamma[0];

  float bq_r[4], ks_r[4], vs_r[2][4];
#pragma unroll
  for (int r = 0; r < 4; ++r) {
    bq_r[r] = bq[16 * w + 4 * quad + r];
    ks_r[r] = Ksum[b * kM + 16 * w + 4 * quad + r] + 1e-6f;
  }
#pragma unroll
  for (int mi = 0; mi < 2; ++mi)
#pragma unroll
    for (int r = 0; r < 4; ++r)
      vs_r[mi][r] = vsum[b * kC + (2 * w + mi) * 16 + 4 * quad + r];

  const float* xrow = x + ((size_t)(b * kC + ch)) * kN;

  for (int ti = 0; ti < 8; ++ti) {
    const int n0 = blockIdx.x * 256 + ti * 32;
    __syncthreads();
    // stage x (ch-fastest only)
    const float4* xg = (const float4*)(xrow + n0 + half * 16);
#pragma unroll
    for (int i = 0; i < 4; ++i) {
      float4 v = xg[i];
      xb_t[half * 16 + 4 * i + 0][ch] = f2bf(v.x);
      xb_t[half * 16 + 4 * i + 1][ch] = f2bf(v.y);
      xb_t[half * 16 + 4 * i + 2][ch] = f2bf(v.z);
      xb_t[half * 16 + 4 * i + 3][ch] = f2bf(v.w);
    }
    __syncthreads();

    // Q projection
    f32x4 acc1[2] = {{0.f, 0.f, 0.f, 0.f}, {0.f, 0.f, 0.f, 0.f}};
    const ushort_t* wqbase = Wqb + (16 * w + l16) * 256 + quad * 8;
#pragma unroll
    for (int ks = 0; ks < 8; ++ks) {
      short8 a = *(const short8*)(wqbase + ks * 32);
      short8 b0 = *(const short8*)&xb_t[l16][ks * 32 + quad * 8];
      short8 b1 = *(const short8*)&xb_t[16 + l16][ks * 32 + quad * 8];
      acc1[0] = MFMA16(a, b0, acc1[0]);
      acc1[1] = MFMA16(a, b1, acc1[1]);
    }
    float q0v[4], q1v[4];
    float ssq0 = 0.f, ssq1 = 0.f, dot0 = 0.f, dot1 = 0.f;
#pragma unroll
    for (int r = 0; r < 4; ++r) {
      q0v[r] = acc1[0][r] + bq_r[r];
      q1v[r] = acc1[1][r] + bq_r[r];
      ssq0 += q0v[r] * q0v[r]; ssq1 += q1v[r] * q1v[r];
      dot0 += q0v[r] * ks_r[r]; dot1 += q1v[r] * ks_r[r];
    }
    ssq0 += __shfl_xor(ssq0, 16); ssq0 += __shfl_xor(ssq0, 32);
    ssq1 += __shfl_xor(ssq1, 16); ssq1 += __shfl_xor(ssq1, 32);
    dot0 += __shfl_xor(dot0, 16); dot0 += __shfl_xor(dot0, 32);
    dot1 += __shfl_xor(dot1, 16); dot1 += __shfl_xor(dot1, 32);
    if (quad == 0) {
      red[w][l16] = ssq0;  red[w][16 + l16] = ssq1;
      red2[w][l16] = dot0; red2[w][16 + l16] = dot1;
    }
    __syncthreads();
    if (t < 32) {
      float s = 0.f, d = 0.f;
#pragma unroll
      for (int ww = 0; ww < 8; ++ww) { s += red[ww][t]; d += red2[ww][t]; }
      float iv = rsqrtf(s);
      inv_s[t] = iv;
      tail_s[t] = 1.f / (16384.f + d * iv);
    }
    __syncthreads();
    {
      const float iv0 = inv_s[l16], iv1 = inv_s[16 + l16];
      ushort_t q0b[4], q1b[4];
#pragma unroll
      for (int r = 0; r < 4; ++r) { q0b[r] = f2bf(q0v[r] * iv0); q1b[r] = f2bf(q1v[r] * iv1); }
      uint2 p0, p1;
      p0.x = (unsigned)q0b[0] | ((unsigned)q0b[1] << 16);
      p0.y = (unsigned)q0b[2] | ((unsigned)q0b[3] << 16);
      p1.x = (unsigned)q1b[0] | ((unsigned)q1b[1] << 16);
      p1.y = (unsigned)q1b[2] | ((unsigned)q1b[3] << 16);
      *(uint2*)&qnb[l16][16 * w + 4 * quad] = p0;
      *(uint2*)&qnb[16 + l16][16 * w + 4 * quad] = p1;
    }
    __syncthreads();

    // out-GEMM: O[256 x 32] = matT * qn  (wave w owns c-tiles 2w, 2w+1)
    f32x4 accO[2][2];
#pragma unroll
    for (int mi = 0; mi < 2; ++mi)
#pragma unroll
      for (int nt = 0; nt < 2; ++nt) accO[mi][nt] = (f32x4){0.f, 0.f, 0.f, 0.f};
    const ushort_t* mrow0 = matT + ((size_t)b * kC + (2 * w) * 16 + l16) * kM + quad * 8;
    const ushort_t* mrow1 = mrow0 + 16 * kM;
#pragma unroll
    for (int ks = 0; ks < 4; ++ks) {
      short8 b0 = *(const short8*)&qnb[l16][ks * 32 + quad * 8];
      short8 b1 = *(const short8*)&qnb[16 + l16][ks * 32 + quad * 8];
      short8 a0 = *(const short8*)(mrow0 + ks * 32);
      short8 a1 = *(const short8*)(mrow1 + ks * 32);
      accO[0][0] = MFMA16(a0, b0, accO[0][0]);
      accO[0][1] = MFMA16(a0, b1, accO[0][1]);
      accO[1][0] = MFMA16(a1, b0, accO[1][0]);
      accO[1][1] = MFMA16(a1, b1, accO[1][1]);
    }
    // epilogue
    const float tl0 = tail_s[l16], tl1 = tail_s[16 + l16];
#pragma unroll
    for (int mi = 0; mi < 2; ++mi) {
#pragma unroll
      for (int r = 0; r < 4; ++r) {
        int c = (2 * w + mi) * 16 + 4 * quad + r;
        size_t base = ((size_t)(b * kC + c)) * kN + n0;
        out[base + l16] = gm * tl0 * (vs_r[mi][r] + accO[mi][0][r]);
        out[base + 16 + l16] = gm * tl1 * (vs_r[mi][r] + accO[mi][1][r]);
      }
    }
  }
}

extern "C" void kernel_launch(void* const* d_in, const int* in_sizes, int n_in,
                              void* d_out, int out_size, void* d_ws, size_t ws_size,
                              hipStream_t stream) {
  (void)in_sizes; (void)n_in; (void)out_size; (void)ws_size;
  const float* x     = (const float*)d_in[0];
  const float* Wq    = (const float*)d_in[1];
  const float* bq    = (const float*)d_in[2];
  const float* Wk    = (const float*)d_in[3];
  const float* bk    = (const float*)d_in[4];
  const float* Wv    = (const float*)d_in[5];
  const float* bv    = (const float*)d_in[6];
  const float* gamma = (const float*)d_in[7];
  float* out = (float*)d_out;

  char* wsb = (char*)d_ws;
  float*    S    = (float*)(wsb + kOffS);
  float*    Ksum = (float*)(wsb + kOffKsum);
  float*    xsum = (float*)(wsb + kOffXsum);
  float*    vsum = (float*)(wsb + kOffVsum);
  ushort_t* Wkb  = (ushort_t*)(wsb + kOffWkb);
  ushort_t* Wqb  = (ushort_t*)(wsb + kOffWqb);
  ushort_t* matT = (ushort_t*)(wsb + kOffMatT);

  k0_init<<<1024, 256, 0, stream>>>(Wq, Wk, (float*)wsb, Wkb, Wqb);
  k1_acc<<<dim3(64, 8), 512, 0, stream>>>(x, bk, Wkb, S, Ksum, xsum);
  k2_matrix<<<64, 256, 0, stream>>>(S, Ksum, xsum, Wv, bv, matT, vsum);
  k3_out<<<dim3(64, 8), 512, 0, stream>>>(x, bq, Wqb, matT, Ksum, vsum, gamma, out);
}

// Round 3
// 344.399 us; speedup vs baseline: 14.9671x; 1.3664x over previous
//
#include <hip/hip_runtime.h>
#include <math.h>

typedef unsigned short ushort_t;
typedef __attribute__((ext_vector_type(4))) float f32x4;
typedef __attribute__((ext_vector_type(8))) short short8;

#define MFMA16(a, b, c) __builtin_amdgcn_mfma_f32_16x16x32_bf16((a), (b), (c), 0, 0, 0)

// Problem dims (fixed)
constexpr int kB = 8;
constexpr int kC = 256;
constexpr int kM = 128;
constexpr int kN = 16384;

// ws layout (bytes, all 256-aligned). Total ~1.65 MB.
constexpr size_t kOffS    = 0;         // fp32 [8][128][256]
constexpr size_t kOffKsum = 1048576;   // fp32 [8][128]
constexpr size_t kOffXsum = 1052672;   // fp32 [8][256]
constexpr size_t kOffVsum = 1060864;   // fp32 [8][256]
constexpr size_t kOffWkb  = 1069056;   // bf16 [128][256]
constexpr size_t kOffWqb  = 1134592;   // bf16 [128][256]
constexpr size_t kOffMatT = 1200128;   // bf16 [8][256][128]  (matrix transposed)

__device__ __forceinline__ ushort_t f2bf(float f) {
  union { float f; unsigned u; } v; v.f = f;
  unsigned r = v.u + 0x7fffu + ((v.u >> 16) & 1u);
  return (ushort_t)(r >> 16);
}
__device__ __forceinline__ float bf2f(ushort_t h) {
  union { float f; unsigned u; } v; v.u = ((unsigned)h) << 16;
  return v.f;
}

// Barrier that drains LDS only (lgkmcnt(0)) and leaves global loads in
// flight — avoids the compiler's vmcnt(0) drain at __syncthreads so the
// register-prefetched staging loads stay outstanding across the barrier.
__device__ __forceinline__ void sync_lds() {
  __atomic_signal_fence(__ATOMIC_SEQ_CST);
  __builtin_amdgcn_s_waitcnt(0xc07f);  // lgkmcnt(0), vmcnt/expcnt untouched
  __builtin_amdgcn_s_barrier();
  __atomic_signal_fence(__ATOMIC_SEQ_CST);
}

// ---------------- K0: zero accumulators + cast weights to bf16 ---------------
__global__ void k0_init(const float* __restrict__ Wq, const float* __restrict__ Wk,
                        float* __restrict__ ws_f, ushort_t* __restrict__ Wkb,
                        ushort_t* __restrict__ Wqb) {
  int i = blockIdx.x * 256 + threadIdx.x;  // 1024 x 256 = 262144 threads
  // zero S (262144 f) + Ksum (1024 f) + xsum (2048 f) contiguous
  for (int j = i; j < 265216; j += 262144) ws_f[j] = 0.0f;
  if (i < kM * kC) {
    Wkb[i] = f2bf(Wk[i]);
    Wqb[i] = f2bf(Wq[i]);
  }
}

// ---------------- K1: K-proj (MFMA) -> L2-norm -> S += Kn * x^T (MFMA) -------
// grid (64, 8), block 512. Each block: 8 tiles of 32 pixels (256 px total).
__global__ __launch_bounds__(512, 2)
void k1_acc(const float* __restrict__ x, const float* __restrict__ bk,
            const ushort_t* __restrict__ Wkb, float* __restrict__ S,
            float* __restrict__ Ksum, float* __restrict__ xsum) {
  __shared__ __align__(16) ushort_t xb_n[256][40];   // [ch][px]  (px-fastest)
  __shared__ __align__(16) ushort_t xb_t[32][264];   // [px][ch]  (ch-fastest)
  __shared__ __align__(16) ushort_t knb[128][40];    // [Krow][px]
  __shared__ __align__(16) float red[32][12];        // [px][wave]

  const int t = threadIdx.x;
  const int b = blockIdx.y;
  const int lane = t & 63, w = t >> 6, quad = lane >> 4, l16 = lane & 15;
  const int r8 = t >> 3;        // row-in-64 (0..63)
  const int px0 = 4 * (t & 7);  // owned pixel group

  float bk_r[4];
#pragma unroll
  for (int r = 0; r < 4; ++r) bk_r[r] = bk[16 * w + 4 * quad + r];

  f32x4 accS[16];
#pragma unroll
  for (int ct = 0; ct < 16; ++ct) accS[ct] = (f32x4){0.f, 0.f, 0.f, 0.f};
  float ksump[4] = {0.f, 0.f, 0.f, 0.f};
  float xs_p[4] = {0.f, 0.f, 0.f, 0.f};

  // staging base: thread covers rows r8 + 64p, pixels px0..px0+3
  const float* xg = x + ((size_t)(b * kC) + r8) * kN + blockIdx.x * 256 + px0;

  float4 bufA[4], bufB[4];
#pragma unroll
  for (int p = 0; p < 4; ++p)
    bufA[p] = *(const float4*)(xg + (size_t)p * 64 * kN);

  auto step = [&](int ti, float4 (&cur)[4], float4 (&nxt)[4]) {
    sync_lds();  // previous tile's LDS consumers done
    if (ti < 7) {
#pragma unroll
      for (int p = 0; p < 4; ++p)
        nxt[p] = *(const float4*)(xg + (size_t)p * 64 * kN + (ti + 1) * 32);
    }
#pragma unroll
    for (int p = 0; p < 4; ++p) {
      float4 v = cur[p];
      const int rp = 64 * p + r8;
      xs_p[p] += v.x + v.y + v.z + v.w;
      ushort_t u0 = f2bf(v.x), u1 = f2bf(v.y), u2 = f2bf(v.z), u3 = f2bf(v.w);
      uint2 pk;
      pk.x = (unsigned)u0 | ((unsigned)u1 << 16);
      pk.y = (unsigned)u2 | ((unsigned)u3 << 16);
      *(uint2*)&xb_n[rp][px0] = pk;
      xb_t[px0 + 0][rp] = u0;
      xb_t[px0 + 1][rp] = u1;
      xb_t[px0 + 2][rp] = u2;
      xb_t[px0 + 3][rp] = u3;
    }
    sync_lds();  // stage done

    // ---- GEMM1: K[128x32] = Wk * x (wave w owns K rows 16w..16w+15) ----
    f32x4 acc1[2] = {{0.f, 0.f, 0.f, 0.f}, {0.f, 0.f, 0.f, 0.f}};
    const ushort_t* wkbase = Wkb + (16 * w + l16) * 256 + quad * 8;
#pragma unroll
    for (int ks = 0; ks < 8; ++ks) {
      short8 a = *(const short8*)(wkbase + ks * 32);
      short8 b0 = *(const short8*)&xb_t[l16][ks * 32 + quad * 8];
      short8 b1 = *(const short8*)&xb_t[16 + l16][ks * 32 + quad * 8];
      acc1[0] = MFMA16(a, b0, acc1[0]);
      acc1[1] = MFMA16(a, b1, acc1[1]);
    }
    float k0v[4], k1v[4];
    float ssq0 = 0.f, ssq1 = 0.f;
#pragma unroll
    for (int r = 0; r < 4; ++r) {
      k0v[r] = acc1[0][r] + bk_r[r];
      k1v[r] = acc1[1][r] + bk_r[r];
      ssq0 += k0v[r] * k0v[r];
      ssq1 += k1v[r] * k1v[r];
    }
    ssq0 += __shfl_xor(ssq0, 16); ssq0 += __shfl_xor(ssq0, 32);
    ssq1 += __shfl_xor(ssq1, 16); ssq1 += __shfl_xor(ssq1, 32);
    if (quad == 0) { red[l16][w] = ssq0; red[16 + l16][w] = ssq1; }
    sync_lds();  // red ready

    // every lane sums the 8 wave-partials itself (no serialized pass)
    f32x4 ra = *(const f32x4*)&red[l16][0];
    f32x4 rb = *(const f32x4*)&red[l16][4];
    f32x4 rc = *(const f32x4*)&red[16 + l16][0];
    f32x4 rd = *(const f32x4*)&red[16 + l16][4];
    const float iv0 = rsqrtf(ra[0] + ra[1] + ra[2] + ra[3] + rb[0] + rb[1] + rb[2] + rb[3]);
    const float iv1 = rsqrtf(rc[0] + rc[1] + rc[2] + rc[3] + rd[0] + rd[1] + rd[2] + rd[3]);
#pragma unroll
    for (int r = 0; r < 4; ++r) {
      float kn0 = k0v[r] * iv0, kn1 = k1v[r] * iv1;
      ksump[r] += kn0 + kn1;
      knb[16 * w + 4 * quad + r][l16] = f2bf(kn0);
      knb[16 * w + 4 * quad + r][16 + l16] = f2bf(kn1);
    }
    // knb rows 16w..16w+15 are wave-private: DS pipe is in-order per wave,
    // so no barrier needed before reading them back.
    __builtin_amdgcn_s_waitcnt(0xc07f);

    // ---- GEMM2: S[128x256] += Kn * x^T (Kdim = 32 px) ----
    short8 a2 = *(const short8*)&knb[16 * w + l16][quad * 8];
#pragma unroll
    for (int ct = 0; ct < 16; ++ct) {
      short8 b2 = *(const short8*)&xb_n[ct * 16 + l16][quad * 8];
      accS[ct] = MFMA16(a2, b2, accS[ct]);
    }
  };

  for (int ti = 0; ti < 8; ti += 2) {
    step(ti, bufA, bufB);
    step(ti + 1, bufB, bufA);
  }

  // ---- flush ----
  float* Sb = S + (size_t)b * kM * kC;
#pragma unroll
  for (int ct = 0; ct < 16; ++ct)
#pragma unroll
    for (int r = 0; r < 4; ++r)
      atomicAdd(&Sb[(16 * w + 4 * quad + r) * 256 + ct * 16 + l16], accS[ct][r]);
#pragma unroll
  for (int r = 0; r < 4; ++r) {
    float v = ksump[r];
    v += __shfl_xor(v, 1); v += __shfl_xor(v, 2);
    v += __shfl_xor(v, 4); v += __shfl_xor(v, 8);
    if (l16 == 0) atomicAdd(&Ksum[b * kM + 16 * w + 4 * quad + r], v);
  }
#pragma unroll
  for (int p = 0; p < 4; ++p) {
    float v = xs_p[p];
    v += __shfl_xor(v, 1); v += __shfl_xor(v, 2); v += __shfl_xor(v, 4);
    if ((t & 7) == 0) atomicAdd(&xsum[b * kC + 64 * p + r8], v);
  }
}

// ---------------- K2: matT = (S*Wv^T + Ksum*bv^T)^T via hi/lo bf16 MFMA ------
// grid 256 (= 8 b x 16 c-tile x 2 m-half), block 256 (4 waves).
// hi/lo split keeps fp32-level accuracy: A*B ~= Ah*Bh + Ah*Bl + Al*Bh.
__global__ __launch_bounds__(256, 4)
void k2_matrix(const float* __restrict__ S, const float* __restrict__ Ksum,
               const float* __restrict__ xsum, const float* __restrict__ Wv,
               const float* __restrict__ bv, ushort_t* __restrict__ matT,
               float* __restrict__ vsum) {
  const int t = threadIdx.x;
  const int lane = t & 63, w = t >> 6, quad = lane >> 4, l16 = lane & 15;
  const int bx = blockIdx.x;
  const int b = bx >> 5, ct = (bx >> 1) & 15, mt = bx & 1;
  const int c0 = ct * 16;
  const int m0 = mt * 64 + w * 16;

  const float* arow = Wv + (size_t)(c0 + l16) * 256 + quad * 8;   // A: Wv rows (c)
  const float* brow = S + ((size_t)b * kM + m0 + l16) * 256 + quad * 8;  // B: S rows (m)
  const bool do_vsum = (mt == 0) && (w == 0);
  const float* xsb = xsum + b * kC + quad * 8;

  f32x4 acc = (f32x4){0.f, 0.f, 0.f, 0.f};
  float vdot = 0.f;

#pragma unroll
  for (int ks = 0; ks < 8; ++ks) {
    float4 a0 = *(const float4*)(arow + ks * 32);
    float4 a1 = *(const float4*)(arow + ks * 32 + 4);
    float4 b0 = *(const float4*)(brow + ks * 32);
    float4 b1 = *(const float4*)(brow + ks * 32 + 4);
    float av[8] = {a0.x, a0.y, a0.z, a0.w, a1.x, a1.y, a1.z, a1.w};
    float bw[8] = {b0.x, b0.y, b0.z, b0.w, b1.x, b1.y, b1.z, b1.w};
    if (do_vsum) {
      float4 x0 = *(const float4*)(xsb + ks * 32);
      float4 x1 = *(const float4*)(xsb + ks * 32 + 4);
      vdot += av[0] * x0.x + av[1] * x0.y + av[2] * x0.z + av[3] * x0.w +
              av[4] * x1.x + av[5] * x1.y + av[6] * x1.z + av[7] * x1.w;
    }
    short8 ah, al, bh, bl;
#pragma unroll
    for (int i = 0; i < 8; ++i) {
      ushort_t h = f2bf(av[i]);
      ah[i] = (short)h;
      al[i] = (short)f2bf(av[i] - bf2f(h));
      ushort_t g = f2bf(bw[i]);
      bh[i] = (short)g;
      bl[i] = (short)f2bf(bw[i] - bf2f(g));
    }
    acc = MFMA16(ah, bh, acc);
    acc = MFMA16(ah, bl, acc);
    acc = MFMA16(al, bh, acc);
  }

  const float ksm = Ksum[b * kM + m0 + l16];
  float4 bv4 = *(const float4*)(bv + c0 + quad * 4);
  float bvv[4] = {bv4.x, bv4.y, bv4.z, bv4.w};
#pragma unroll
  for (int r = 0; r < 4; ++r) {
    const int c = c0 + 4 * quad + r;
    matT[((size_t)b * kC + c) * kM + m0 + l16] = f2bf(acc[r] + ksm * bvv[r]);
  }
  if (do_vsum) {
    vdot += __shfl_xor(vdot, 16);
    vdot += __shfl_xor(vdot, 32);
    if (quad == 0)
      vsum[b * kC + c0 + l16] = vdot + 16384.f * bv[c0 + l16];
  }
}

// ---------------- K3: Q-proj -> norm/tailor -> out = g*t*(vsum + matT*qn) ----
// grid (64, 8), block 512.
__global__ __launch_bounds__(512, 2)
void k3_out(const float* __restrict__ x, const float* __restrict__ bq,
            const ushort_t* __restrict__ Wqb, const ushort_t* __restrict__ matT,
            const float* __restrict__ Ksum, const float* __restrict__ vsum,
            const float* __restrict__ gamma, float* __restrict__ out) {
  __shared__ __align__(16) ushort_t xb_t[32][264];   // [px][ch]
  __shared__ __align__(16) ushort_t qnb[32][136];    // [px][m]
  __shared__ __align__(16) float red[32][12];
  __shared__ __align__(16) float red2[32][12];

  const int t = threadIdx.x;
  const int b = blockIdx.y;
  const int lane = t & 63, w = t >> 6, quad = lane >> 4, l16 = lane & 15;
  const int r8 = t >> 3;
  const int px0 = 4 * (t & 7);
  const float gm = gamma[0];

  float bq_r[4], ks_r[4], vs_r[2][4];
#pragma unroll
  for (int r = 0; r < 4; ++r) {
    bq_r[r] = bq[16 * w + 4 * quad + r];
    ks_r[r] = Ksum[b * kM + 16 * w + 4 * quad + r] + 1e-6f;
  }
#pragma unroll
  for (int mi = 0; mi < 2; ++mi)
#pragma unroll
    for (int r = 0; r < 4; ++r)
      vs_r[mi][r] = vsum[b * kC + (2 * w + mi) * 16 + 4 * quad + r];

  const float* xg = x + ((size_t)(b * kC) + r8) * kN + blockIdx.x * 256 + px0;

  float4 bufA[4], bufB[4];
#pragma unroll
  for (int p = 0; p < 4; ++p)
    bufA[p] = *(const float4*)(xg + (size_t)p * 64 * kN);

  auto step = [&](int ti, float4 (&cur)[4], float4 (&nxt)[4]) {
    const int n0 = blockIdx.x * 256 + ti * 32;
    sync_lds();
    if (ti < 7) {
#pragma unroll
      for (int p = 0; p < 4; ++p)
        nxt[p] = *(const float4*)(xg + (size_t)p * 64 * kN + (ti + 1) * 32);
    }
#pragma unroll
    for (int p = 0; p < 4; ++p) {
      float4 v = cur[p];
      const int rp = 64 * p + r8;
      xb_t[px0 + 0][rp] = f2bf(v.x);
      xb_t[px0 + 1][rp] = f2bf(v.y);
      xb_t[px0 + 2][rp] = f2bf(v.z);
      xb_t[px0 + 3][rp] = f2bf(v.w);
    }
    sync_lds();

    // Q projection
    f32x4 acc1[2] = {{0.f, 0.f, 0.f, 0.f}, {0.f, 0.f, 0.f, 0.f}};
    const ushort_t* wqbase = Wqb + (16 * w + l16) * 256 + quad * 8;
#pragma unroll
    for (int ks = 0; ks < 8; ++ks) {
      short8 a = *(const short8*)(wqbase + ks * 32);
      short8 b0 = *(const short8*)&xb_t[l16][ks * 32 + quad * 8];
      short8 b1 = *(const short8*)&xb_t[16 + l16][ks * 32 + quad * 8];
      acc1[0] = MFMA16(a, b0, acc1[0]);
      acc1[1] = MFMA16(a, b1, acc1[1]);
    }
    float q0v[4], q1v[4];
    float ssq0 = 0.f, ssq1 = 0.f, dot0 = 0.f, dot1 = 0.f;
#pragma unroll
    for (int r = 0; r < 4; ++r) {
      q0v[r] = acc1[0][r] + bq_r[r];
      q1v[r] = acc1[1][r] + bq_r[r];
      ssq0 += q0v[r] * q0v[r]; ssq1 += q1v[r] * q1v[r];
      dot0 += q0v[r] * ks_r[r]; dot1 += q1v[r] * ks_r[r];
    }
    ssq0 += __shfl_xor(ssq0, 16); ssq0 += __shfl_xor(ssq0, 32);
    ssq1 += __shfl_xor(ssq1, 16); ssq1 += __shfl_xor(ssq1, 32);
    dot0 += __shfl_xor(dot0, 16); dot0 += __shfl_xor(dot0, 32);
    dot1 += __shfl_xor(dot1, 16); dot1 += __shfl_xor(dot1, 32);
    if (quad == 0) {
      red[l16][w] = ssq0;  red[16 + l16][w] = ssq1;
      red2[l16][w] = dot0; red2[16 + l16][w] = dot1;
    }
    sync_lds();
    f32x4 ra = *(const f32x4*)&red[l16][0];
    f32x4 rb = *(const f32x4*)&red[l16][4];
    f32x4 rc = *(const f32x4*)&red[16 + l16][0];
    f32x4 rd = *(const f32x4*)&red[16 + l16][4];
    f32x4 da = *(const f32x4*)&red2[l16][0];
    f32x4 db = *(const f32x4*)&red2[l16][4];
    f32x4 dc = *(const f32x4*)&red2[16 + l16][0];
    f32x4 dd = *(const f32x4*)&red2[16 + l16][4];
    const float iv0 = rsqrtf(ra[0] + ra[1] + ra[2] + ra[3] + rb[0] + rb[1] + rb[2] + rb[3]);
    const float iv1 = rsqrtf(rc[0] + rc[1] + rc[2] + rc[3] + rd[0] + rd[1] + rd[2] + rd[3]);
    const float d0 = da[0] + da[1] + da[2] + da[3] + db[0] + db[1] + db[2] + db[3];
    const float d1 = dc[0] + dc[1] + dc[2] + dc[3] + dd[0] + dd[1] + dd[2] + dd[3];
    const float tl0 = 1.f / (16384.f + d0 * iv0);
    const float tl1 = 1.f / (16384.f + d1 * iv1);
    {
      ushort_t q0b[4], q1b[4];
#pragma unroll
      for (int r = 0; r < 4; ++r) {
        q0b[r] = f2bf(q0v[r] * iv0);
        q1b[r] = f2bf(q1v[r] * iv1);
      }
      uint2 p0, p1;
      p0.x = (unsigned)q0b[0] | ((unsigned)q0b[1] << 16);
      p0.y = (unsigned)q0b[2] | ((unsigned)q0b[3] << 16);
      p1.x = (unsigned)q1b[0] | ((unsigned)q1b[1] << 16);
      p1.y = (unsigned)q1b[2] | ((unsigned)q1b[3] << 16);
      *(uint2*)&qnb[l16][16 * w + 4 * quad] = p0;
      *(uint2*)&qnb[16 + l16][16 * w + 4 * quad] = p1;
    }
    sync_lds();  // qnb is read cross-wave

    // out-GEMM: O[256 x 32] = matT * qn  (wave w owns c-tiles 2w, 2w+1)
    f32x4 accO[2][2];
#pragma unroll
    for (int mi = 0; mi < 2; ++mi)
#pragma unroll
      for (int nt = 0; nt < 2; ++nt) accO[mi][nt] = (f32x4){0.f, 0.f, 0.f, 0.f};
    const ushort_t* mrow0 = matT + ((size_t)b * kC + (2 * w) * 16 + l16) * kM + quad * 8;
    const ushort_t* mrow1 = mrow0 + 16 * kM;
#pragma unroll
    for (int ks = 0; ks < 4; ++ks) {
      short8 b0 = *(const short8*)&qnb[l16][ks * 32 + quad * 8];
      short8 b1 = *(const short8*)&qnb[16 + l16][ks * 32 + quad * 8];
      short8 a0 = *(const short8*)(mrow0 + ks * 32);
      short8 a1 = *(const short8*)(mrow1 + ks * 32);
      accO[0][0] = MFMA16(a0, b0, accO[0][0]);
      accO[0][1] = MFMA16(a0, b1, accO[0][1]);
      accO[1][0] = MFMA16(a1, b0, accO[1][0]);
      accO[1][1] = MFMA16(a1, b1, accO[1][1]);
    }
#pragma unroll
    for (int mi = 0; mi < 2; ++mi) {
#pragma unroll
      for (int r = 0; r < 4; ++r) {
        const int c = (2 * w + mi) * 16 + 4 * quad + r;
        size_t base = ((size_t)(b * kC + c)) * kN + n0;
        out[base + l16] = gm * tl0 * (vs_r[mi][r] + accO[mi][0][r]);
        out[base + 16 + l16] = gm * tl1 * (vs_r[mi][r] + accO[mi][1][r]);
      }
    }
  };

  for (int ti = 0; ti < 8; ti += 2) {
    step(ti, bufA, bufB);
    step(ti + 1, bufB, bufA);
  }
}

extern "C" void kernel_launch(void* const* d_in, const int* in_sizes, int n_in,
                              void* d_out, int out_size, void* d_ws, size_t ws_size,
                              hipStream_t stream) {
  (void)in_sizes; (void)n_in; (void)out_size; (void)ws_size;
  const float* x     = (const float*)d_in[0];
  const float* Wq    = (const float*)d_in[1];
  const float* bq    = (const float*)d_in[2];
  const float* Wk    = (const float*)d_in[3];
  const float* bk    = (const float*)d_in[4];
  const float* Wv    = (const float*)d_in[5];
  const float* bv    = (const float*)d_in[6];
  const float* gamma = (const float*)d_in[7];
  float* out = (float*)d_out;

  char* wsb = (char*)d_ws;
  float*    S    = (float*)(wsb + kOffS);
  float*    Ksum = (float*)(wsb + kOffKsum);
  float*    xsum = (float*)(wsb + kOffXsum);
  float*    vsum = (float*)(wsb + kOffVsum);
  ushort_t* Wkb  = (ushort_t*)(wsb + kOffWkb);
  ushort_t* Wqb  = (ushort_t*)(wsb + kOffWqb);
  ushort_t* matT = (ushort_t*)(wsb + kOffMatT);

  k0_init<<<1024, 256, 0, stream>>>(Wq, Wk, (float*)wsb, Wkb, Wqb);
  k1_acc<<<dim3(64, 8), 512, 0, stream>>>(x, bk, Wkb, S, Ksum, xsum);
  k2_matrix<<<256, 256, 0, stream>>>(S, Ksum, xsum, Wv, bv, matT, vsum);
  k3_out<<<dim3(64, 8), 512, 0, stream>>>(x, bq, Wqb, matT, Ksum, vsum, gamma, out);
}